// Round 10
// baseline (213.518 us; speedup 1.0000x reference)
//
#include <hip/hip_runtime.h>
#include <cstdint>
#include <cstddef>

#define S_LEN 4096
#define NB 8
#define NH 12
#define DMODEL 768
#define DHEAD 64
#define M_TOT (NB * S_LEN)      /* 32768 */
#define INV_SQRT_DH 0.125f
#define WSZ (DMODEL * DMODEL)

typedef __attribute__((ext_vector_type(4))) float f32x4;
typedef __attribute__((ext_vector_type(8))) short bf16x8;

__device__ inline float bf2f(unsigned short h) {
    union { unsigned int u; float f; } v; v.u = ((unsigned int)h) << 16; return v.f;
}
__device__ inline unsigned short f2bf(float f) {
    union { float f; unsigned int u; } v; v.f = f;
    unsigned int r = v.u + 0x7FFFu + ((v.u >> 16) & 1u);
    return (unsigned short)(r >> 16);
}

__device__ inline void gload_lds16(const unsigned short* gp, void* lp) {
    __builtin_amdgcn_global_load_lds((const __attribute__((address_space(1))) void*)gp,
                                     (__attribute__((address_space(3))) void*)lp,
                                     16, 0, 0);
}

// ---------------- prep: hs cvt + all weights/biases, one launch ----------------
__global__ void prep_all(const float* __restrict__ hs,
                         const float* __restrict__ Wq, const float* __restrict__ Wk,
                         const float* __restrict__ Wt, const float* __restrict__ Wqa,
                         const float* __restrict__ bq, const float* __restrict__ bk,
                         unsigned short* __restrict__ hs_bf,
                         unsigned short* __restrict__ Wqk_bf, unsigned short* __restrict__ Wt_bf,
                         unsigned short* __restrict__ Wqa_bf, float* __restrict__ bqk) {
    int bid = blockIdx.x;
    int t = threadIdx.x;
    if (bid < 24576) {
        int off = bid * 1024 + t * 4;
        float4 v = *(const float4*)(hs + off);
        ushort4 o;
        o.x = f2bf(v.x); o.y = f2bf(v.y); o.z = f2bf(v.z); o.w = f2bf(v.w);
        *(ushort4*)(hs_bf + off) = o;
        return;
    }
    bid -= 24576;
    if (bid < 1728) {
        const float* src = (bid < 576) ? Wq : ((bid < 1152) ? Wk : Wt);
        unsigned short* dst = (bid < 576) ? Wqk_bf : ((bid < 1152) ? (Wqk_bf + WSZ) : Wt_bf);
        int off = (bid % 576) * 1024 + t * 4;
        float4 v = *(const float4*)(src + off);
        ushort4 o;
        o.x = f2bf(v.x); o.y = f2bf(v.y); o.z = f2bf(v.z); o.w = f2bf(v.w);
        *(ushort4*)(dst + off) = o;
    } else if (bid < 1740) {
        int off = (bid - 1728) * 1024 + t * 4;
        int h = off / DMODEL;
        ushort4 o = {0, 0, 0, 0};
        if (h < NH) {
            float4 v = *(const float4*)(Wqa + off);
            o.x = f2bf(v.x); o.y = f2bf(v.y); o.z = f2bf(v.z); o.w = f2bf(v.w);
        }
        *(ushort4*)(Wqa_bf + off) = o;
    } else {
        int off = (bid - 1740) * 1024 + t * 4;
        if (off < 2 * DMODEL) {
            const float* src = (off < DMODEL) ? (bq + off) : (bk + off - DMODEL);
            *(float4*)(bqk + off) = *(const float4*)src;
        }
    }
}

// ---------------- shared phase macros ----------------
#define PH_MID() do { __builtin_amdgcn_s_barrier(); \
    asm volatile("s_waitcnt lgkmcnt(0)"); \
    __builtin_amdgcn_sched_barrier(0); \
    __builtin_amdgcn_s_setprio(1); } while (0)
#define PH_END() do { __builtin_amdgcn_s_setprio(0); \
    __builtin_amdgcn_s_barrier(); } while (0)

// ================= GEMM A: 256x256, 8-load/K-tile (qk projection) =================
#define STG_A(q, kt, BO) gload_lds16(pA + (size_t)((q) * 64) * 768 + (kt) * 64, \
                                     lds + (BO) + (q) * 8192 + wOff)
#define STG_B(q, kt, BO) gload_lds16(pB + (size_t)((q) * 64) * 768 + (kt) * 64, \
                                     lds + (BO) + 32768 + (q) * 8192 + wOff)

#define LD_A(mh, BO) do { _Pragma("unroll") for (int mm = 0; mm < 4; ++mm) { \
    a[mm][0] = *(const bf16x8*)(lds + (BO) + aRd0 + ((mh) * 4 + mm) * 2048); \
    a[mm][1] = *(const bf16x8*)(lds + (BO) + aRd1 + ((mh) * 4 + mm) * 2048); } } while (0)
#define LD_B(nh, BO) do { _Pragma("unroll") for (int nn = 0; nn < 2; ++nn) { \
    b[(nh) * 2 + nn][0] = *(const bf16x8*)(lds + (BO) + bRd0 + ((nh) * 2 + nn) * 2048); \
    b[(nh) * 2 + nn][1] = *(const bf16x8*)(lds + (BO) + bRd1 + ((nh) * 2 + nn) * 2048); } } while (0)
#define MFMAQ(mh, nh) do { _Pragma("unroll") for (int mm = 0; mm < 4; ++mm) \
    _Pragma("unroll") for (int nn = 0; nn < 2; ++nn) { \
        acc[(mh) * 4 + mm][(nh) * 2 + nn] = __builtin_amdgcn_mfma_f32_16x16x32_bf16( \
            a[mm][0], b[(nh) * 2 + nn][0], acc[(mh) * 4 + mm][(nh) * 2 + nn], 0, 0, 0); \
        acc[(mh) * 4 + mm][(nh) * 2 + nn] = __builtin_amdgcn_mfma_f32_16x16x32_bf16( \
            a[mm][1], b[(nh) * 2 + nn][1], acc[(mh) * 4 + mm][(nh) * 2 + nn], 0, 0, 0); } } while (0)

__global__ __launch_bounds__(512, 2) void gemm8(
    const unsigned short* __restrict__ A,
    const unsigned short* __restrict__ Bw,
    const float* __restrict__ bias,
    unsigned short* __restrict__ outBf, int ldoBf,
    int ntn)
{
    __shared__ __align__(16) char lds[131072];

    int nwg = gridDim.x;
    int bid = blockIdx.x;
    int cpx = nwg >> 3;
    int swz = (bid & 7) * cpx + (bid >> 3);
    int bidn = swz % ntn, bidm = swz / ntn;
    int m0 = bidm * 256, n0 = bidn * 256;

    int t = threadIdx.x;
    int w = t >> 6, lane = t & 63;
    int lr = lane & 15, lk = lane >> 4;
    int wr = w >> 2, wc = w & 3;
    int wOff = w << 10;

    int srow = t >> 3;
    int sblk = (t & 7) ^ (srow & 7);
    const unsigned short* pA = A + (size_t)(m0 + srow) * 768 + sblk * 8;
    const unsigned short* pB = Bw + (size_t)(n0 + srow) * 768 + sblk * 8;

    int sx = lr & 7;
    int aRd0 = (wr * 128 + lr) * 128 + ((0 + lk) ^ sx) * 16;
    int aRd1 = (wr * 128 + lr) * 128 + ((4 + lk) ^ sx) * 16;
    int bRd0 = 32768 + (wc * 64 + lr) * 128 + ((0 + lk) ^ sx) * 16;
    int bRd1 = 32768 + (wc * 64 + lr) * 128 + ((4 + lk) ^ sx) * 16;

    f32x4 acc[8][4];
#pragma unroll
    for (int m = 0; m < 8; ++m)
#pragma unroll
        for (int n = 0; n < 4; ++n)
            acc[m][n] = (f32x4){0.f, 0.f, 0.f, 0.f};
    bf16x8 a[4][2], b[4][2];

    STG_A(0, 0, 0); STG_A(1, 0, 0); STG_A(2, 0, 0); STG_A(3, 0, 0);
    STG_B(0, 0, 0); STG_B(1, 0, 0); STG_B(2, 0, 0); STG_B(3, 0, 0);
    STG_A(0, 1, 65536); STG_A(2, 1, 65536);
    STG_B(0, 1, 65536); STG_B(1, 1, 65536); STG_B(2, 1, 65536); STG_B(3, 1, 65536);
    asm volatile("s_waitcnt vmcnt(6)");
    __builtin_amdgcn_s_barrier();

    for (int i = 0; i < 6; ++i) {
        int ktE = 2 * i, ktO = 2 * i + 1;
        int s2 = (i < 5);
        LD_A(0, 0); LD_B(0, 0);
        STG_A(1, ktO, 65536); STG_A(3, ktO, 65536);
        PH_MID(); MFMAQ(0, 0); PH_END();
        LD_B(1, 0);
        if (s2) { STG_A(0, ktE + 2, 0); STG_A(2, ktE + 2, 0); }
        PH_MID(); MFMAQ(0, 1); PH_END();
        LD_A(1, 0);
        if (s2) { STG_B(0, ktE + 2, 0); STG_B(1, ktE + 2, 0); }
        PH_MID(); MFMAQ(1, 1); PH_END();
        if (s2) { STG_B(2, ktE + 2, 0); STG_B(3, ktE + 2, 0); }
        PH_MID(); MFMAQ(1, 0);
        __builtin_amdgcn_s_setprio(0);
        if (s2) { asm volatile("s_waitcnt vmcnt(6)"); }
        else    { asm volatile("s_waitcnt vmcnt(0)"); }
        __builtin_amdgcn_s_barrier();
        LD_A(0, 65536); LD_B(0, 65536);
        if (s2) { STG_A(1, ktE + 2, 0); STG_A(3, ktE + 2, 0); }
        PH_MID(); MFMAQ(0, 0); PH_END();
        LD_B(1, 65536);
        if (s2) { STG_A(0, ktO + 2, 65536); STG_A(2, ktO + 2, 65536); }
        PH_MID(); MFMAQ(0, 1); PH_END();
        LD_A(1, 65536);
        if (s2) { STG_B(0, ktO + 2, 65536); STG_B(1, ktO + 2, 65536); }
        PH_MID(); MFMAQ(1, 1); PH_END();
        if (s2) { STG_B(2, ktO + 2, 65536); STG_B(3, ktO + 2, 65536); }
        PH_MID(); MFMAQ(1, 0);
        __builtin_amdgcn_s_setprio(0);
        if (s2) { asm volatile("s_waitcnt vmcnt(6)"); }
        __builtin_amdgcn_s_barrier();
    }

#pragma unroll
    for (int m = 0; m < 8; ++m) {
        int gr0 = m0 + wr * 128 + m * 16 + lk * 4;
#pragma unroll
        for (int n = 0; n < 4; ++n) {
            int gc = n0 + wc * 64 + n * 16 + lr;
            float bv = bias[gc];
#pragma unroll
            for (int r = 0; r < 4; ++r) {
                int gr = gr0 + r;
                outBf[(size_t)gr * ldoBf + gc] = f2bf(acc[m][n][r] + bv);
            }
        }
    }
}

// ================= GEMM B: 256x128, BK=64, 3-buffer, 1 barrier-pair/K-tile =================
// 512 thr (8 waves, 4m x 2n, 64x64 out each). 12 K-tiles, buf t%3 (48 KB: A 32 + B 16).
// Per tile: stage 6 of t+2 (A0..A3,B0,B1) at tile start; all 16 ds_read_b128/wave; ONE
// barrier+lgkm drain; 32 MFMA/wave; end vmcnt(6)+barrier.
// INVARIANT entering tile t: outstanding = 6 = ALL of tile t+1 (prologue t0+t1=12, vmcnt(6)).
// End vmcnt(6): 6 old (t+1) + 6 new (t+2) -> retires whole t+1 before anything reads it.
// t=10 end: vmcnt(0) retires t11. WAR: buf (t+2)%3 last read in tile t-1, complete before
// its end barrier; stages for t+2 issue after that barrier.
#define STG6_A(q, kt, SB) gload_lds16(pA + (size_t)((q) * 64) * 1536 + (kt) * 64, \
                                      lds + (SB) + (q) * 8192 + wOff)
#define STG6_B(q, kt, SB) gload_lds16(pB + (size_t)((q) * 64) * 768 + (kt) * 64, \
                                      lds + (SB) + 32768 + (q) * 8192 + wOff)

__global__ __launch_bounds__(512, 2) void gemm3(
    const unsigned short* __restrict__ A,      // q in qk_bf, ld 1536
    const unsigned short* __restrict__ W8,     // 8x[768][768] gated Wt
    const float* __restrict__ bias,
    float* __restrict__ outF,
    const unsigned short* __restrict__ resid)  // q, ld 1536
{
    __shared__ __align__(16) char lds[147456];  // 3 x 48 KB

    int nwg = gridDim.x;                       // 768
    int bid = blockIdx.x;
    int cpx = nwg >> 3;
    int swz = (bid & 7) * cpx + (bid >> 3);
    int bidn = swz % 6, bidm = swz / 6;
    int m0 = bidm * 256, n0 = bidn * 128;

    const unsigned short* Bw = W8 + (size_t)(m0 >> 12) * WSZ;

    int t = threadIdx.x;
    int w = t >> 6, lane = t & 63;
    int lr = lane & 15, lk = lane >> 4;
    int wr = w >> 1, wc = w & 1;
    int wOff = w << 10;

    int srow = t >> 3;
    int sblk = (t & 7) ^ (srow & 7);
    const unsigned short* pA = A + (size_t)(m0 + srow) * 1536 + sblk * 8;
    const unsigned short* pB = Bw + (size_t)(n0 + srow) * 768 + sblk * 8;

    int sx = lr & 7;
    int aRd0 = (wr * 64 + lr) * 128 + ((0 + lk) ^ sx) * 16;
    int aRd1 = (wr * 64 + lr) * 128 + ((4 + lk) ^ sx) * 16;
    int bRd0 = 32768 + (wc * 64 + lr) * 128 + ((0 + lk) ^ sx) * 16;
    int bRd1 = 32768 + (wc * 64 + lr) * 128 + ((4 + lk) ^ sx) * 16;

    f32x4 acc[4][4];
#pragma unroll
    for (int m = 0; m < 4; ++m)
#pragma unroll
        for (int n = 0; n < 4; ++n)
            acc[m][n] = (f32x4){0.f, 0.f, 0.f, 0.f};
    bf16x8 a[4][2], b[4][2];

    // prologue: stage tile0 -> buf0, tile1 -> buf1 (12 loads), retire tile0
    STG6_A(0, 0, 0); STG6_A(1, 0, 0); STG6_A(2, 0, 0); STG6_A(3, 0, 0);
    STG6_B(0, 0, 0); STG6_B(1, 0, 0);
    STG6_A(0, 1, 49152); STG6_A(1, 1, 49152); STG6_A(2, 1, 49152); STG6_A(3, 1, 49152);
    STG6_B(0, 1, 49152); STG6_B(1, 1, 49152);
    asm volatile("s_waitcnt vmcnt(6)");
    __builtin_amdgcn_s_barrier();

#define TILE6(tt, BUF, SB) do { \
    if ((tt) <= 9) { STG6_A(0, (tt) + 2, SB); STG6_A(1, (tt) + 2, SB); \
                     STG6_A(2, (tt) + 2, SB); STG6_A(3, (tt) + 2, SB); \
                     STG6_B(0, (tt) + 2, SB); STG6_B(1, (tt) + 2, SB); } \
    _Pragma("unroll") for (int mm = 0; mm < 4; ++mm) { \
        a[mm][0] = *(const bf16x8*)(lds + (BUF) + aRd0 + mm * 2048); \
        a[mm][1] = *(const bf16x8*)(lds + (BUF) + aRd1 + mm * 2048); } \
    _Pragma("unroll") for (int nn = 0; nn < 4; ++nn) { \
        b[nn][0] = *(const bf16x8*)(lds + (BUF) + bRd0 + nn * 2048); \
        b[nn][1] = *(const bf16x8*)(lds + (BUF) + bRd1 + nn * 2048); } \
    PH_MID(); \
    _Pragma("unroll") for (int mm = 0; mm < 4; ++mm) \
    _Pragma("unroll") for (int nn = 0; nn < 4; ++nn) { \
        acc[mm][nn] = __builtin_amdgcn_mfma_f32_16x16x32_bf16(a[mm][0], b[nn][0], acc[mm][nn], 0, 0, 0); \
        acc[mm][nn] = __builtin_amdgcn_mfma_f32_16x16x32_bf16(a[mm][1], b[nn][1], acc[mm][nn], 0, 0, 0); } \
    __builtin_amdgcn_s_setprio(0); \
    if ((tt) <= 9)       { asm volatile("s_waitcnt vmcnt(6)"); } \
    else if ((tt) == 10) { asm volatile("s_waitcnt vmcnt(0)"); } \
    __builtin_amdgcn_s_barrier(); \
} while (0)

    for (int ii = 0; ii < 4; ++ii) {
        int tb = ii * 3;
        TILE6(tb + 0, 0,     98304);
        TILE6(tb + 1, 49152, 0);
        TILE6(tb + 2, 98304, 49152);
    }

    // direct epilogue: f32 out + resid
#pragma unroll
    for (int m = 0; m < 4; ++m) {
        int gr0 = m0 + wr * 64 + m * 16 + lk * 4;
#pragma unroll
        for (int n = 0; n < 4; ++n) {
            int gc = n0 + wc * 64 + n * 16 + lr;
            float bv = bias[gc];
#pragma unroll
            for (int r = 0; r < 4; ++r) {
                int gr = gr0 + r;
                float v = acc[m][n][r] + bv + bf2f(resid[(size_t)gr * 1536 + gc]);
                outF[(size_t)gr * DMODEL + gc] = v;
            }
        }
    }
}

// ---------------- qfs logits: [M,16(12)] = q @ Wqa^T ----------------
__global__ __launch_bounds__(256) void qfs_kernel(
    const unsigned short* __restrict__ q, int ldq,
    const unsigned short* __restrict__ wqa,
    const float* __restrict__ bqa,
    const float* __restrict__ mask,
    float* __restrict__ qfs)
{
    int t = threadIdx.x;
    int w = t >> 6, lane = t & 63;
    int lr = lane & 15, lk = lane >> 4;
    int m0 = blockIdx.x * 64 + w * 16;

    f32x4 acc = (f32x4){0.f, 0.f, 0.f, 0.f};
    for (int k0 = 0; k0 < DMODEL; k0 += 32) {
        bf16x8 av = *(const bf16x8*)&q[(size_t)(m0 + lr) * ldq + k0 + lk * 8];
        bf16x8 bv = *(const bf16x8*)&wqa[lr * DMODEL + k0 + lk * 8];
        acc = __builtin_amdgcn_mfma_f32_16x16x32_bf16(av, bv, acc, 0, 0, 0);
    }
    if (lr < NH) {
        float bv = bqa[lr];
#pragma unroll
        for (int r = 0; r < 4; ++r) {
            int m = m0 + lk * 4 + r;
            int b_ = m >> 12;
            int s = m & (S_LEN - 1);
            qfs[((size_t)b_ * NH + lr) * S_LEN + s] = acc[r] * INV_SQRT_DH + bv + mask[b_ * S_LEN + s];
        }
    }
}

// ---------------- chunked softmax-pool over precomputed logits (pool1) ----------------
__global__ __launch_bounds__(256) void pool1_kernel(
    const float* __restrict__ logits,          // [96][4096]
    const unsigned short* __restrict__ qk,     // ld 1536
    float* __restrict__ parts)                 // [96][8][72]
{
    int bid = blockIdx.x;
    int bh = bid >> 3, c = bid & 7;
    int b = bh / NH, h = bh % NH;
    int s0 = c * 512;
    int t = threadIdx.x;

    __shared__ float w[512];
    __shared__ float red[8];
    __shared__ float part[4][64];

    const float* lg = logits + (size_t)bh * S_LEN + s0;
    float l0 = lg[t], l1 = lg[t + 256];
    float m = fmaxf(l0, l1);
#pragma unroll
    for (int off = 32; off; off >>= 1) m = fmaxf(m, __shfl_xor(m, off));
    if ((t & 63) == 0) red[t >> 6] = m;
    __syncthreads();
    float M = fmaxf(fmaxf(red[0], red[1]), fmaxf(red[2], red[3]));
    float w0 = __expf(l0 - M), w1 = __expf(l1 - M);
    w[t] = w0; w[t + 256] = w1;
    float z = w0 + w1;
#pragma unroll
    for (int off = 32; off; off >>= 1) z += __shfl_xor(z, off);
    if ((t & 63) == 0) red[4 + (t >> 6)] = z;
    __syncthreads();
    float Z = red[4] + red[5] + red[6] + red[7];

    int dblk = t & 7, rgrp = t >> 3;
    const unsigned short* xp = qk + ((size_t)(b * S_LEN + s0)) * 1536 + h * DHEAD + dblk * 8;
    float acc[8];
#pragma unroll
    for (int e = 0; e < 8; ++e) acc[e] = 0.f;
    for (int j = 0; j < 16; ++j) {
        int r = j * 32 + rgrp;
        bf16x8 v = *(const bf16x8*)(xp + (size_t)r * 1536);
        float wr = w[r];
#pragma unroll
        for (int e = 0; e < 8; ++e) acc[e] += wr * bf2f((unsigned short)v[e]);
    }
#pragma unroll
    for (int off = 8; off <= 32; off <<= 1)
#pragma unroll
        for (int e = 0; e < 8; ++e) acc[e] += __shfl_xor(acc[e], off);
    if ((t & 63) < 8) {
#pragma unroll
        for (int e = 0; e < 8; ++e) part[t >> 6][(t & 7) * 8 + e] = acc[e];
    }
    __syncthreads();
    float* dst = parts + ((size_t)bh * 8 + c) * 72;
    if (t < 64) dst[t] = part[0][t] + part[1][t] + part[2][t] + part[3][t];
    else if (t == 64) dst[64] = M;
    else if (t == 65) dst[65] = Z;
}

// ---------------- fused qks+pool2 ----------------
__global__ __launch_bounds__(256) void pool2_kernel(
    const float* __restrict__ parts1,          // [96][8][72]
    const unsigned short* __restrict__ qk,     // ld 1536, k at +768
    const float* __restrict__ mask,
    float* __restrict__ parts2)                // [96][8][72]
{
    int bid = blockIdx.x;
    int bh = bid >> 3, c = bid & 7;
    int b = bh / NH, h = bh % NH;
    int s0 = c * 512;
    int t = threadIdx.x;

    __shared__ float pq[64];
    __shared__ float w[512];
    __shared__ float red[8];
    __shared__ float part[4][64];

    if (t < 64) {
        const float* p1 = parts1 + (size_t)bh * 8 * 72;
        float M1 = -1e30f;
#pragma unroll
        for (int cc = 0; cc < 8; ++cc) M1 = fmaxf(M1, p1[cc * 72 + 64]);
        float Z1 = 0.f, a1 = 0.f;
#pragma unroll
        for (int cc = 0; cc < 8; ++cc) {
            float f = __expf(p1[cc * 72 + 64] - M1);
            Z1 += f * p1[cc * 72 + 65];
            a1 += f * p1[cc * 72 + t];
        }
        pq[t] = a1 / Z1;
    }
    __syncthreads();

    int dblk = t & 7, rgrp = t >> 3;
    float pq8[8];
#pragma unroll
    for (int e = 0; e < 8; ++e) pq8[e] = pq[dblk * 8 + e];

    const unsigned short* kp = qk + ((size_t)(b * S_LEN + s0)) * 1536 + DMODEL + h * DHEAD + dblk * 8;

    for (int j = 0; j < 16; ++j) {
        int r = j * 32 + rgrp;
        bf16x8 v = *(const bf16x8*)(kp + (size_t)r * 1536);
        float d = 0.f;
#pragma unroll
        for (int e = 0; e < 8; ++e) d += bf2f((unsigned short)v[e]) * pq8[e];
        d += __shfl_xor(d, 1); d += __shfl_xor(d, 2); d += __shfl_xor(d, 4);
        if (dblk == 0) w[r] = d * INV_SQRT_DH + mask[b * S_LEN + s0 + r];
    }
    __syncthreads();

    float l0 = w[t], l1 = w[t + 256];
    float m = fmaxf(l0, l1);
#pragma unroll
    for (int off = 32; off; off >>= 1) m = fmaxf(m, __shfl_xor(m, off));
    if ((t & 63) == 0) red[t >> 6] = m;
    __syncthreads();
    float M = fmaxf(fmaxf(red[0], red[1]), fmaxf(red[2], red[3]));
    float w0 = __expf(l0 - M), w1 = __expf(l1 - M);
    float z = w0 + w1;
#pragma unroll
    for (int off = 32; off; off >>= 1) z += __shfl_xor(z, off);
    if ((t & 63) == 0) red[4 + (t >> 6)] = z;
    __syncthreads();
    w[t] = w0; w[t + 256] = w1;
    __syncthreads();
    float Z = red[4] + red[5] + red[6] + red[7];

    float acc[8];
#pragma unroll
    for (int e = 0; e < 8; ++e) acc[e] = 0.f;
    for (int j = 0; j < 16; ++j) {
        int r = j * 32 + rgrp;
        bf16x8 v = *(const bf16x8*)(kp + (size_t)r * 1536);
        float wr = w[r];
#pragma unroll
        for (int e = 0; e < 8; ++e) acc[e] += wr * bf2f((unsigned short)v[e]);
    }
#pragma unroll
    for (int off = 8; off <= 32; off <<= 1)
#pragma unroll
        for (int e = 0; e < 8; ++e) acc[e] += __shfl_xor(acc[e], off);
    if ((t & 63) < 8) {
#pragma unroll
        for (int e = 0; e < 8; ++e) part[t >> 6][(t & 7) * 8 + e] = acc[e];
    }
    __syncthreads();
    float* dst = parts2 + ((size_t)bh * 8 + c) * 72;
    if (t < 64) dst[t] = part[0][t] + part[1][t] + part[2][t] + part[3][t];
    else if (t == 64) dst[64] = M;
    else if (t == 65) dst[65] = Z;
}

// ---------------- gated weights: W8[b] = Wt * pooled_k[b][col] ----------------
__global__ __launch_bounds__(256) void gatedw_kernel(
    const float* __restrict__ parts2,
    const unsigned short* __restrict__ Wt_bf,
    unsigned short* __restrict__ W8)
{
    int bid = blockIdx.x;
    int b = bid / 96, rg = bid % 96;
    int t = threadIdx.x;

    __shared__ float mhc[96], Mh[12], fac[96], zh[12], pk[768];

    if (t < 96) mhc[t] = parts2[((size_t)(b * NH + t / 8) * 8 + (t & 7)) * 72 + 64];
    __syncthreads();
    if (t < 12) {
        float M = -1e30f;
#pragma unroll
        for (int cc = 0; cc < 8; ++cc) M = fmaxf(M, mhc[t * 8 + cc]);
        Mh[t] = M;
    }
    __syncthreads();
    if (t < 96) fac[t] = __expf(mhc[t] - Mh[t / 8]);
    __syncthreads();
    if (t < 12) {
        float Zm = 0.f;
#pragma unroll
        for (int cc = 0; cc < 8; ++cc)
            Zm += fac[t * 8 + cc] * parts2[((size_t)(b * NH + t) * 8 + cc) * 72 + 65];
        zh[t] = Zm;
    }
    __syncthreads();
#pragma unroll
    for (int j = 0; j < 3; ++j) {
        int col = t + 256 * j;
        int h = col >> 6, d = col & 63;
        const float* p2 = parts2 + (size_t)(b * NH + h) * 8 * 72;
        float v = 0.f;
#pragma unroll
        for (int cc = 0; cc < 8; ++cc) v += fac[h * 8 + cc] * p2[cc * 72 + d];
        pk[col] = v / zh[h];
    }
    __syncthreads();
#pragma unroll
    for (int j = 0; j < 3; ++j) {
        int idx = j * 2048 + t * 8;
        int r = rg * 8 + idx / DMODEL, k = idx % DMODEL;
        bf16x8 wv = *(const bf16x8*)(Wt_bf + (size_t)r * DMODEL + k);
        bf16x8 o;
#pragma unroll
        for (int e = 0; e < 8; ++e)
            o[e] = (short)f2bf(bf2f((unsigned short)wv[e]) * pk[k + e]);
        *(bf16x8*)(W8 + (size_t)b * WSZ + (size_t)r * DMODEL + k) = o;
    }
}

// ---------------- launch ----------------
extern "C" void kernel_launch(void* const* d_in, const int* in_sizes, int n_in,
                              void* d_out, int out_size, void* d_ws, size_t ws_size,
                              hipStream_t stream) {
    const float* hs   = (const float*)d_in[0];
    const float* mask = (const float*)d_in[1];
    const float* Wq   = (const float*)d_in[2];
    const float* bq   = (const float*)d_in[3];
    const float* Wqa  = (const float*)d_in[4];
    const float* bqa  = (const float*)d_in[5];
    const float* Wk   = (const float*)d_in[6];
    const float* bk   = (const float*)d_in[7];
    const float* Wt   = (const float*)d_in[8];
    const float* bt   = (const float*)d_in[9];
    float* out = (float*)d_out;

    char* ws = (char*)d_ws;
    unsigned short* qk_bf  = (unsigned short*)(ws);                   // [32768][1536] bf16
    unsigned short* hs_bf  = (unsigned short*)(ws + 100663296);       // [32768][768]; dead after gemm1
    unsigned short* W8     = hs_bf;                                   // overlays hs_bf
    unsigned short* Wqk_bf = (unsigned short*)(ws + 150994944);       // [1536][768]
    unsigned short* Wt_bf  = (unsigned short*)(ws + 153354240);       // [768][768]
    unsigned short* Wqa_bf = (unsigned short*)(ws + 154533888);       // [16][768]
    float* bqk    = (float*)(ws + 154558464);                         // [1536]
    float* qfs    = (float*)(ws + 154564608);                         // [96][4096]
    float* parts1 = (float*)(ws + 156137472);                         // [96][8][72]
    float* parts2 = (float*)(ws + 156358656);                         // [96][8][72]

    prep_all<<<26318, 256, 0, stream>>>(hs, Wq, Wk, Wt, Wqa, bq, bk,
                                        hs_bf, Wqk_bf, Wt_bf, Wqa_bf, bqk);

    // q|k projection: M=32768, N=1536, K=768
    gemm8<<<(M_TOT / 256) * 6, 512, 0, stream>>>(
        hs_bf, Wqk_bf, bqk, qk_bf, 2 * DMODEL, 6);

    qfs_kernel<<<M_TOT / 64, 256, 0, stream>>>(qk_bf, 2 * DMODEL, Wqa_bf, bqa, mask, qfs);
    pool1_kernel<<<NB * NH * 8, 256, 0, stream>>>(qfs, qk_bf, parts1);
    pool2_kernel<<<NB * NH * 8, 256, 0, stream>>>(parts1, qk_bf, mask, parts2);
    gatedw_kernel<<<NB * 96, 256, 0, stream>>>(parts2, Wt_bf, W8);

    // out = q @ (Wt*pk_b)^T + bt + q : M=32768, N=768 (256x128, 1 pair/tile), K=768
    gemm3<<<(M_TOT / 256) * 6, 512, 0, stream>>>(
        qk_bf, W8, bt, out, qk_bf);
}

// Round 11
// 212.360 us; speedup vs baseline: 1.0055x; 1.0055x over previous
//
#include <hip/hip_runtime.h>
#include <cstdint>
#include <cstddef>

#define S_LEN 4096
#define NB 8
#define NH 12
#define DMODEL 768
#define DHEAD 64
#define M_TOT (NB * S_LEN)      /* 32768 */
#define INV_SQRT_DH 0.125f
#define WSZ (DMODEL * DMODEL)

typedef __attribute__((ext_vector_type(4))) float f32x4;
typedef __attribute__((ext_vector_type(8))) short bf16x8;

__device__ inline float bf2f(unsigned short h) {
    union { unsigned int u; float f; } v; v.u = ((unsigned int)h) << 16; return v.f;
}
__device__ inline unsigned short f2bf(float f) {
    union { float f; unsigned int u; } v; v.f = f;
    unsigned int r = v.u + 0x7FFFu + ((v.u >> 16) & 1u);
    return (unsigned short)(r >> 16);
}

__device__ inline void gload_lds16(const unsigned short* gp, void* lp) {
    __builtin_amdgcn_global_load_lds((const __attribute__((address_space(1))) void*)gp,
                                     (__attribute__((address_space(3))) void*)lp,
                                     16, 0, 0);
}

// ---------------- prep: hs cvt + all weights/biases, one launch ----------------
__global__ void prep_all(const float* __restrict__ hs,
                         const float* __restrict__ Wq, const float* __restrict__ Wk,
                         const float* __restrict__ Wt, const float* __restrict__ Wqa,
                         const float* __restrict__ bq, const float* __restrict__ bk,
                         unsigned short* __restrict__ hs_bf,
                         unsigned short* __restrict__ Wqk_bf, unsigned short* __restrict__ Wt_bf,
                         unsigned short* __restrict__ Wqa_bf, float* __restrict__ bqk) {
    int bid = blockIdx.x;
    int t = threadIdx.x;
    if (bid < 24576) {
        int off = bid * 1024 + t * 4;
        float4 v = *(const float4*)(hs + off);
        ushort4 o;
        o.x = f2bf(v.x); o.y = f2bf(v.y); o.z = f2bf(v.z); o.w = f2bf(v.w);
        *(ushort4*)(hs_bf + off) = o;
        return;
    }
    bid -= 24576;
    if (bid < 1728) {
        const float* src = (bid < 576) ? Wq : ((bid < 1152) ? Wk : Wt);
        unsigned short* dst = (bid < 576) ? Wqk_bf : ((bid < 1152) ? (Wqk_bf + WSZ) : Wt_bf);
        int off = (bid % 576) * 1024 + t * 4;
        float4 v = *(const float4*)(src + off);
        ushort4 o;
        o.x = f2bf(v.x); o.y = f2bf(v.y); o.z = f2bf(v.z); o.w = f2bf(v.w);
        *(ushort4*)(dst + off) = o;
    } else if (bid < 1740) {
        int off = (bid - 1728) * 1024 + t * 4;
        int h = off / DMODEL;
        ushort4 o = {0, 0, 0, 0};
        if (h < NH) {
            float4 v = *(const float4*)(Wqa + off);
            o.x = f2bf(v.x); o.y = f2bf(v.y); o.z = f2bf(v.z); o.w = f2bf(v.w);
        }
        *(ushort4*)(Wqa_bf + off) = o;
    } else {
        int off = (bid - 1740) * 1024 + t * 4;
        if (off < 2 * DMODEL) {
            const float* src = (off < DMODEL) ? (bq + off) : (bk + off - DMODEL);
            *(float4*)(bqk + off) = *(const float4*)src;
        }
    }
}

// ---------------- shared phase macros ----------------
#define PH_MID() do { __builtin_amdgcn_s_barrier(); \
    asm volatile("s_waitcnt lgkmcnt(0)"); \
    __builtin_amdgcn_sched_barrier(0); \
    __builtin_amdgcn_s_setprio(1); } while (0)
#define PH_END() do { __builtin_amdgcn_s_setprio(0); \
    __builtin_amdgcn_s_barrier(); } while (0)

// ================= GEMM A: 256x256, 8-load/K-tile (qk projection) =================
// Output split: bidn 0..2 -> q_c[32768][768]; bidn 3..5 -> k_c[32768][768].
#define STG_A(q, kt, BO) gload_lds16(pA + (size_t)((q) * 64) * 768 + (kt) * 64, \
                                     lds + (BO) + (q) * 8192 + wOff)
#define STG_B(q, kt, BO) gload_lds16(pB + (size_t)((q) * 64) * 768 + (kt) * 64, \
                                     lds + (BO) + 32768 + (q) * 8192 + wOff)

#define LD_A(mh, BO) do { _Pragma("unroll") for (int mm = 0; mm < 4; ++mm) { \
    a[mm][0] = *(const bf16x8*)(lds + (BO) + aRd0 + ((mh) * 4 + mm) * 2048); \
    a[mm][1] = *(const bf16x8*)(lds + (BO) + aRd1 + ((mh) * 4 + mm) * 2048); } } while (0)
#define LD_B(nh, BO) do { _Pragma("unroll") for (int nn = 0; nn < 2; ++nn) { \
    b[(nh) * 2 + nn][0] = *(const bf16x8*)(lds + (BO) + bRd0 + ((nh) * 2 + nn) * 2048); \
    b[(nh) * 2 + nn][1] = *(const bf16x8*)(lds + (BO) + bRd1 + ((nh) * 2 + nn) * 2048); } } while (0)
#define MFMAQ(mh, nh) do { _Pragma("unroll") for (int mm = 0; mm < 4; ++mm) \
    _Pragma("unroll") for (int nn = 0; nn < 2; ++nn) { \
        acc[(mh) * 4 + mm][(nh) * 2 + nn] = __builtin_amdgcn_mfma_f32_16x16x32_bf16( \
            a[mm][0], b[(nh) * 2 + nn][0], acc[(mh) * 4 + mm][(nh) * 2 + nn], 0, 0, 0); \
        acc[(mh) * 4 + mm][(nh) * 2 + nn] = __builtin_amdgcn_mfma_f32_16x16x32_bf16( \
            a[mm][1], b[(nh) * 2 + nn][1], acc[(mh) * 4 + mm][(nh) * 2 + nn], 0, 0, 0); } } while (0)

__global__ __launch_bounds__(512, 2) void gemm8(
    const unsigned short* __restrict__ A,
    const unsigned short* __restrict__ Bw,
    const float* __restrict__ bias,
    unsigned short* __restrict__ qOut,
    unsigned short* __restrict__ kOut,
    int ntn)
{
    __shared__ __align__(16) char lds[131072];

    int nwg = gridDim.x;
    int bid = blockIdx.x;
    int cpx = nwg >> 3;
    int swz = (bid & 7) * cpx + (bid >> 3);
    int bidn = swz % ntn, bidm = swz / ntn;
    int m0 = bidm * 256, n0 = bidn * 256;

    int t = threadIdx.x;
    int w = t >> 6, lane = t & 63;
    int lr = lane & 15, lk = lane >> 4;
    int wr = w >> 2, wc = w & 3;
    int wOff = w << 10;

    int srow = t >> 3;
    int sblk = (t & 7) ^ (srow & 7);
    const unsigned short* pA = A + (size_t)(m0 + srow) * 768 + sblk * 8;
    const unsigned short* pB = Bw + (size_t)(n0 + srow) * 768 + sblk * 8;

    int sx = lr & 7;
    int aRd0 = (wr * 128 + lr) * 128 + ((0 + lk) ^ sx) * 16;
    int aRd1 = (wr * 128 + lr) * 128 + ((4 + lk) ^ sx) * 16;
    int bRd0 = 32768 + (wc * 64 + lr) * 128 + ((0 + lk) ^ sx) * 16;
    int bRd1 = 32768 + (wc * 64 + lr) * 128 + ((4 + lk) ^ sx) * 16;

    f32x4 acc[8][4];
#pragma unroll
    for (int m = 0; m < 8; ++m)
#pragma unroll
        for (int n = 0; n < 4; ++n)
            acc[m][n] = (f32x4){0.f, 0.f, 0.f, 0.f};
    bf16x8 a[4][2], b[4][2];

    STG_A(0, 0, 0); STG_A(1, 0, 0); STG_A(2, 0, 0); STG_A(3, 0, 0);
    STG_B(0, 0, 0); STG_B(1, 0, 0); STG_B(2, 0, 0); STG_B(3, 0, 0);
    STG_A(0, 1, 65536); STG_A(2, 1, 65536);
    STG_B(0, 1, 65536); STG_B(1, 1, 65536); STG_B(2, 1, 65536); STG_B(3, 1, 65536);
    asm volatile("s_waitcnt vmcnt(6)");
    __builtin_amdgcn_s_barrier();

    for (int i = 0; i < 6; ++i) {
        int ktE = 2 * i, ktO = 2 * i + 1;
        int s2 = (i < 5);
        LD_A(0, 0); LD_B(0, 0);
        STG_A(1, ktO, 65536); STG_A(3, ktO, 65536);
        PH_MID(); MFMAQ(0, 0); PH_END();
        LD_B(1, 0);
        if (s2) { STG_A(0, ktE + 2, 0); STG_A(2, ktE + 2, 0); }
        PH_MID(); MFMAQ(0, 1); PH_END();
        LD_A(1, 0);
        if (s2) { STG_B(0, ktE + 2, 0); STG_B(1, ktE + 2, 0); }
        PH_MID(); MFMAQ(1, 1); PH_END();
        if (s2) { STG_B(2, ktE + 2, 0); STG_B(3, ktE + 2, 0); }
        PH_MID(); MFMAQ(1, 0);
        __builtin_amdgcn_s_setprio(0);
        if (s2) { asm volatile("s_waitcnt vmcnt(6)"); }
        else    { asm volatile("s_waitcnt vmcnt(0)"); }
        __builtin_amdgcn_s_barrier();
        LD_A(0, 65536); LD_B(0, 65536);
        if (s2) { STG_A(1, ktE + 2, 0); STG_A(3, ktE + 2, 0); }
        PH_MID(); MFMAQ(0, 0); PH_END();
        LD_B(1, 65536);
        if (s2) { STG_A(0, ktO + 2, 65536); STG_A(2, ktO + 2, 65536); }
        PH_MID(); MFMAQ(0, 1); PH_END();
        LD_A(1, 65536);
        if (s2) { STG_B(0, ktO + 2, 65536); STG_B(1, ktO + 2, 65536); }
        PH_MID(); MFMAQ(1, 1); PH_END();
        if (s2) { STG_B(2, ktO + 2, 65536); STG_B(3, ktO + 2, 65536); }
        PH_MID(); MFMAQ(1, 0);
        __builtin_amdgcn_s_setprio(0);
        if (s2) { asm volatile("s_waitcnt vmcnt(6)"); }
        __builtin_amdgcn_s_barrier();
    }

    // direct epilogue -> compact q_c / k_c (ld 768)
    unsigned short* outBf = (bidn < 3) ? qOut : kOut;
    int nc0 = (bidn < 3) ? n0 : (n0 - 768);
#pragma unroll
    for (int m = 0; m < 8; ++m) {
        int gr0 = m0 + wr * 128 + m * 16 + lk * 4;
#pragma unroll
        for (int n = 0; n < 4; ++n) {
            int gc = n0 + wc * 64 + n * 16 + lr;
            int oc = nc0 + wc * 64 + n * 16 + lr;
            float bv = bias[gc];
#pragma unroll
            for (int r = 0; r < 4; ++r) {
                int gr = gr0 + r;
                outBf[(size_t)gr * 768 + oc] = f2bf(acc[m][n][r] + bv);
            }
        }
    }
}

// ================= GEMM B: 256x128, BK=64, 3-buffer, 1 barrier-pair/K-tile =================
// A = q_c (ld 768 — identical geometry to gemm8's A). Ledger identical to R10 (passing):
// INVARIANT entering tile t: outstanding = 6 = ALL of tile t+1. End vmcnt(6) retires t+1.
// t=10 end: vmcnt(0). WAR on buf (t+2)%3 safe.
#define STG6_A(q, kt, SB) gload_lds16(pA + (size_t)((q) * 64) * 768 + (kt) * 64, \
                                      lds + (SB) + (q) * 8192 + wOff)
#define STG6_B(q, kt, SB) gload_lds16(pB + (size_t)((q) * 64) * 768 + (kt) * 64, \
                                      lds + (SB) + 32768 + (q) * 8192 + wOff)

__global__ __launch_bounds__(512, 2) void gemm3(
    const unsigned short* __restrict__ A,      // q_c, ld 768
    const unsigned short* __restrict__ W8,     // 8x[768][768] gated Wt
    const float* __restrict__ bias,
    float* __restrict__ outF,
    const unsigned short* __restrict__ resid)  // q_c, ld 768
{
    __shared__ __align__(16) char lds[147456];  // 3 x 48 KB

    int nwg = gridDim.x;                       // 768
    int bid = blockIdx.x;
    int cpx = nwg >> 3;
    int swz = (bid & 7) * cpx + (bid >> 3);
    int bidn = swz % 6, bidm = swz / 6;
    int m0 = bidm * 256, n0 = bidn * 128;

    const unsigned short* Bw = W8 + (size_t)(m0 >> 12) * WSZ;

    int t = threadIdx.x;
    int w = t >> 6, lane = t & 63;
    int lr = lane & 15, lk = lane >> 4;
    int wr = w >> 1, wc = w & 1;
    int wOff = w << 10;

    int srow = t >> 3;
    int sblk = (t & 7) ^ (srow & 7);
    const unsigned short* pA = A + (size_t)(m0 + srow) * 768 + sblk * 8;
    const unsigned short* pB = Bw + (size_t)(n0 + srow) * 768 + sblk * 8;

    int sx = lr & 7;
    int aRd0 = (wr * 64 + lr) * 128 + ((0 + lk) ^ sx) * 16;
    int aRd1 = (wr * 64 + lr) * 128 + ((4 + lk) ^ sx) * 16;
    int bRd0 = 32768 + (wc * 64 + lr) * 128 + ((0 + lk) ^ sx) * 16;
    int bRd1 = 32768 + (wc * 64 + lr) * 128 + ((4 + lk) ^ sx) * 16;

    f32x4 acc[4][4];
#pragma unroll
    for (int m = 0; m < 4; ++m)
#pragma unroll
        for (int n = 0; n < 4; ++n)
            acc[m][n] = (f32x4){0.f, 0.f, 0.f, 0.f};
    bf16x8 a[4][2], b[4][2];

    STG6_A(0, 0, 0); STG6_A(1, 0, 0); STG6_A(2, 0, 0); STG6_A(3, 0, 0);
    STG6_B(0, 0, 0); STG6_B(1, 0, 0);
    STG6_A(0, 1, 49152); STG6_A(1, 1, 49152); STG6_A(2, 1, 49152); STG6_A(3, 1, 49152);
    STG6_B(0, 1, 49152); STG6_B(1, 1, 49152);
    asm volatile("s_waitcnt vmcnt(6)");
    __builtin_amdgcn_s_barrier();

#define TILE6(tt, BUF, SB) do { \
    if ((tt) <= 9) { STG6_A(0, (tt) + 2, SB); STG6_A(1, (tt) + 2, SB); \
                     STG6_A(2, (tt) + 2, SB); STG6_A(3, (tt) + 2, SB); \
                     STG6_B(0, (tt) + 2, SB); STG6_B(1, (tt) + 2, SB); } \
    _Pragma("unroll") for (int mm = 0; mm < 4; ++mm) { \
        a[mm][0] = *(const bf16x8*)(lds + (BUF) + aRd0 + mm * 2048); \
        a[mm][1] = *(const bf16x8*)(lds + (BUF) + aRd1 + mm * 2048); } \
    _Pragma("unroll") for (int nn = 0; nn < 4; ++nn) { \
        b[nn][0] = *(const bf16x8*)(lds + (BUF) + bRd0 + nn * 2048); \
        b[nn][1] = *(const bf16x8*)(lds + (BUF) + bRd1 + nn * 2048); } \
    PH_MID(); \
    _Pragma("unroll") for (int mm = 0; mm < 4; ++mm) \
    _Pragma("unroll") for (int nn = 0; nn < 4; ++nn) { \
        acc[mm][nn] = __builtin_amdgcn_mfma_f32_16x16x32_bf16(a[mm][0], b[nn][0], acc[mm][nn], 0, 0, 0); \
        acc[mm][nn] = __builtin_amdgcn_mfma_f32_16x16x32_bf16(a[mm][1], b[nn][1], acc[mm][nn], 0, 0, 0); } \
    __builtin_amdgcn_s_setprio(0); \
    if ((tt) <= 9)       { asm volatile("s_waitcnt vmcnt(6)"); } \
    else if ((tt) == 10) { asm volatile("s_waitcnt vmcnt(0)"); } \
    __builtin_amdgcn_s_barrier(); \
} while (0)

    for (int ii = 0; ii < 4; ++ii) {
        int tb = ii * 3;
        TILE6(tb + 0, 0,     98304);
        TILE6(tb + 1, 49152, 0);
        TILE6(tb + 2, 98304, 49152);
    }

    // direct epilogue: f32 out + resid (q_c, ld 768)
#pragma unroll
    for (int m = 0; m < 4; ++m) {
        int gr0 = m0 + wr * 64 + m * 16 + lk * 4;
#pragma unroll
        for (int n = 0; n < 4; ++n) {
            int gc = n0 + wc * 64 + n * 16 + lr;
            float bv = bias[gc];
#pragma unroll
            for (int r = 0; r < 4; ++r) {
                int gr = gr0 + r;
                float v = acc[m][n][r] + bv + bf2f(resid[(size_t)gr * 768 + gc]);
                outF[(size_t)gr * DMODEL + gc] = v;
            }
        }
    }
}

// ---------------- qfs logits: [M,16(12)] = q @ Wqa^T (q_c, ld 768) ----------------
__global__ __launch_bounds__(256) void qfs_kernel(
    const unsigned short* __restrict__ q,
    const unsigned short* __restrict__ wqa,
    const float* __restrict__ bqa,
    const float* __restrict__ mask,
    float* __restrict__ qfs)
{
    int t = threadIdx.x;
    int w = t >> 6, lane = t & 63;
    int lr = lane & 15, lk = lane >> 4;
    int m0 = blockIdx.x * 64 + w * 16;

    f32x4 acc = (f32x4){0.f, 0.f, 0.f, 0.f};
    for (int k0 = 0; k0 < DMODEL; k0 += 32) {
        bf16x8 av = *(const bf16x8*)&q[(size_t)(m0 + lr) * 768 + k0 + lk * 8];
        bf16x8 bv = *(const bf16x8*)&wqa[lr * DMODEL + k0 + lk * 8];
        acc = __builtin_amdgcn_mfma_f32_16x16x32_bf16(av, bv, acc, 0, 0, 0);
    }
    if (lr < NH) {
        float bv = bqa[lr];
#pragma unroll
        for (int r = 0; r < 4; ++r) {
            int m = m0 + lk * 4 + r;
            int b_ = m >> 12;
            int s = m & (S_LEN - 1);
            qfs[((size_t)b_ * NH + lr) * S_LEN + s] = acc[r] * INV_SQRT_DH + bv + mask[b_ * S_LEN + s];
        }
    }
}

// ---------------- chunked softmax-pool over precomputed logits (pool1, q_c ld 768) -------
__global__ __launch_bounds__(256) void pool1_kernel(
    const float* __restrict__ logits,          // [96][4096]
    const unsigned short* __restrict__ qc,     // [32768][768]
    float* __restrict__ parts)                 // [96][8][72]
{
    int bid = blockIdx.x;
    int bh = bid >> 3, c = bid & 7;
    int b = bh / NH, h = bh % NH;
    int s0 = c * 512;
    int t = threadIdx.x;

    __shared__ float w[512];
    __shared__ float red[8];
    __shared__ float part[4][64];

    const float* lg = logits + (size_t)bh * S_LEN + s0;
    float l0 = lg[t], l1 = lg[t + 256];
    float m = fmaxf(l0, l1);
#pragma unroll
    for (int off = 32; off; off >>= 1) m = fmaxf(m, __shfl_xor(m, off));
    if ((t & 63) == 0) red[t >> 6] = m;
    __syncthreads();
    float M = fmaxf(fmaxf(red[0], red[1]), fmaxf(red[2], red[3]));
    float w0 = __expf(l0 - M), w1 = __expf(l1 - M);
    w[t] = w0; w[t + 256] = w1;
    float z = w0 + w1;
#pragma unroll
    for (int off = 32; off; off >>= 1) z += __shfl_xor(z, off);
    if ((t & 63) == 0) red[4 + (t >> 6)] = z;
    __syncthreads();
    float Z = red[4] + red[5] + red[6] + red[7];

    int dblk = t & 7, rgrp = t >> 3;
    const unsigned short* xp = qc + ((size_t)(b * S_LEN + s0)) * 768 + h * DHEAD + dblk * 8;
    float acc[8];
#pragma unroll
    for (int e = 0; e < 8; ++e) acc[e] = 0.f;
    for (int j = 0; j < 16; ++j) {
        int r = j * 32 + rgrp;
        bf16x8 v = *(const bf16x8*)(xp + (size_t)r * 768);
        float wr = w[r];
#pragma unroll
        for (int e = 0; e < 8; ++e) acc[e] += wr * bf2f((unsigned short)v[e]);
    }
#pragma unroll
    for (int off = 8; off <= 32; off <<= 1)
#pragma unroll
        for (int e = 0; e < 8; ++e) acc[e] += __shfl_xor(acc[e], off);
    if ((t & 63) < 8) {
#pragma unroll
        for (int e = 0; e < 8; ++e) part[t >> 6][(t & 7) * 8 + e] = acc[e];
    }
    __syncthreads();
    float* dst = parts + ((size_t)bh * 8 + c) * 72;
    if (t < 64) dst[t] = part[0][t] + part[1][t] + part[2][t] + part[3][t];
    else if (t == 64) dst[64] = M;
    else if (t == 65) dst[65] = Z;
}

// ---------------- fused qks+pool2 (k_c ld 768) ----------------
__global__ __launch_bounds__(256) void pool2_kernel(
    const float* __restrict__ parts1,          // [96][8][72]
    const unsigned short* __restrict__ kc,     // [32768][768]
    const float* __restrict__ mask,
    float* __restrict__ parts2)                // [96][8][72]
{
    int bid = blockIdx.x;
    int bh = bid >> 3, c = bid & 7;
    int b = bh / NH, h = bh % NH;
    int s0 = c * 512;
    int t = threadIdx.x;

    __shared__ float pq[64];
    __shared__ float w[512];
    __shared__ float red[8];
    __shared__ float part[4][64];

    if (t < 64) {
        const float* p1 = parts1 + (size_t)bh * 8 * 72;
        float M1 = -1e30f;
#pragma unroll
        for (int cc = 0; cc < 8; ++cc) M1 = fmaxf(M1, p1[cc * 72 + 64]);
        float Z1 = 0.f, a1 = 0.f;
#pragma unroll
        for (int cc = 0; cc < 8; ++cc) {
            float f = __expf(p1[cc * 72 + 64] - M1);
            Z1 += f * p1[cc * 72 + 65];
            a1 += f * p1[cc * 72 + t];
        }
        pq[t] = a1 / Z1;
    }
    __syncthreads();

    int dblk = t & 7, rgrp = t >> 3;
    float pq8[8];
#pragma unroll
    for (int e = 0; e < 8; ++e) pq8[e] = pq[dblk * 8 + e];

    const unsigned short* kp = kc + ((size_t)(b * S_LEN + s0)) * 768 + h * DHEAD + dblk * 8;

    for (int j = 0; j < 16; ++j) {
        int r = j * 32 + rgrp;
        bf16x8 v = *(const bf16x8*)(kp + (size_t)r * 768);
        float d = 0.f;
#pragma unroll
        for (int e = 0; e < 8; ++e) d += bf2f((unsigned short)v[e]) * pq8[e];
        d += __shfl_xor(d, 1); d += __shfl_xor(d, 2); d += __shfl_xor(d, 4);
        if (dblk == 0) w[r] = d * INV_SQRT_DH + mask[b * S_LEN + s0 + r];
    }
    __syncthreads();

    float l0 = w[t], l1 = w[t + 256];
    float m = fmaxf(l0, l1);
#pragma unroll
    for (int off = 32; off; off >>= 1) m = fmaxf(m, __shfl_xor(m, off));
    if ((t & 63) == 0) red[t >> 6] = m;
    __syncthreads();
    float M = fmaxf(fmaxf(red[0], red[1]), fmaxf(red[2], red[3]));
    float w0 = __expf(l0 - M), w1 = __expf(l1 - M);
    float z = w0 + w1;
#pragma unroll
    for (int off = 32; off; off >>= 1) z += __shfl_xor(z, off);
    if ((t & 63) == 0) red[4 + (t >> 6)] = z;
    __syncthreads();
    w[t] = w0; w[t + 256] = w1;
    __syncthreads();
    float Z = red[4] + red[5] + red[6] + red[7];

    float acc[8];
#pragma unroll
    for (int e = 0; e < 8; ++e) acc[e] = 0.f;
    for (int j = 0; j < 16; ++j) {
        int r = j * 32 + rgrp;
        bf16x8 v = *(const bf16x8*)(kp + (size_t)r * 768);
        float wr = w[r];
#pragma unroll
        for (int e = 0; e < 8; ++e) acc[e] += wr * bf2f((unsigned short)v[e]);
    }
#pragma unroll
    for (int off = 8; off <= 32; off <<= 1)
#pragma unroll
        for (int e = 0; e < 8; ++e) acc[e] += __shfl_xor(acc[e], off);
    if ((t & 63) < 8) {
#pragma unroll
        for (int e = 0; e < 8; ++e) part[t >> 6][(t & 7) * 8 + e] = acc[e];
    }
    __syncthreads();
    float* dst = parts2 + ((size_t)bh * 8 + c) * 72;
    if (t < 64) dst[t] = part[0][t] + part[1][t] + part[2][t] + part[3][t];
    else if (t == 64) dst[64] = M;
    else if (t == 65) dst[65] = Z;
}

// ---------------- gated weights: W8[b] = Wt * pooled_k[b][col] ----------------
__global__ __launch_bounds__(256) void gatedw_kernel(
    const float* __restrict__ parts2,
    const unsigned short* __restrict__ Wt_bf,
    unsigned short* __restrict__ W8)
{
    int bid = blockIdx.x;
    int b = bid / 96, rg = bid % 96;
    int t = threadIdx.x;

    __shared__ float mhc[96], Mh[12], fac[96], zh[12], pk[768];

    if (t < 96) mhc[t] = parts2[((size_t)(b * NH + t / 8) * 8 + (t & 7)) * 72 + 64];
    __syncthreads();
    if (t < 12) {
        float M = -1e30f;
#pragma unroll
        for (int cc = 0; cc < 8; ++cc) M = fmaxf(M, mhc[t * 8 + cc]);
        Mh[t] = M;
    }
    __syncthreads();
    if (t < 96) fac[t] = __expf(mhc[t] - Mh[t / 8]);
    __syncthreads();
    if (t < 12) {
        float Zm = 0.f;
#pragma unroll
        for (int cc = 0; cc < 8; ++cc)
            Zm += fac[t * 8 + cc] * parts2[((size_t)(b * NH + t) * 8 + cc) * 72 + 65];
        zh[t] = Zm;
    }
    __syncthreads();
#pragma unroll
    for (int j = 0; j < 3; ++j) {
        int col = t + 256 * j;
        int h = col >> 6, d = col & 63;
        const float* p2 = parts2 + (size_t)(b * NH + h) * 8 * 72;
        float v = 0.f;
#pragma unroll
        for (int cc = 0; cc < 8; ++cc) v += fac[h * 8 + cc] * p2[cc * 72 + d];
        pk[col] = v / zh[h];
    }
    __syncthreads();
#pragma unroll
    for (int j = 0; j < 3; ++j) {
        int idx = j * 2048 + t * 8;
        int r = rg * 8 + idx / DMODEL, k = idx % DMODEL;
        bf16x8 wv = *(const bf16x8*)(Wt_bf + (size_t)r * DMODEL + k);
        bf16x8 o;
#pragma unroll
        for (int e = 0; e < 8; ++e)
            o[e] = (short)f2bf(bf2f((unsigned short)wv[e]) * pk[k + e]);
        *(bf16x8*)(W8 + (size_t)b * WSZ + (size_t)r * DMODEL + k) = o;
    }
}

// ---------------- launch ----------------
extern "C" void kernel_launch(void* const* d_in, const int* in_sizes, int n_in,
                              void* d_out, int out_size, void* d_ws, size_t ws_size,
                              hipStream_t stream) {
    const float* hs   = (const float*)d_in[0];
    const float* mask = (const float*)d_in[1];
    const float* Wq   = (const float*)d_in[2];
    const float* bq   = (const float*)d_in[3];
    const float* Wqa  = (const float*)d_in[4];
    const float* bqa  = (const float*)d_in[5];
    const float* Wk   = (const float*)d_in[6];
    const float* bk   = (const float*)d_in[7];
    const float* Wt   = (const float*)d_in[8];
    const float* bt   = (const float*)d_in[9];
    float* out = (float*)d_out;

    char* ws = (char*)d_ws;
    unsigned short* q_c    = (unsigned short*)(ws);                   // [32768][768] bf16
    unsigned short* k_c    = (unsigned short*)(ws + 50331648);        // [32768][768] bf16
    unsigned short* hs_bf  = (unsigned short*)(ws + 100663296);       // [32768][768]; dead after gemm8
    unsigned short* W8     = hs_bf;                                   // overlays hs_bf
    unsigned short* Wqk_bf = (unsigned short*)(ws + 150994944);       // [1536][768]
    unsigned short* Wt_bf  = (unsigned short*)(ws + 153354240);       // [768][768]
    unsigned short* Wqa_bf = (unsigned short*)(ws + 154533888);       // [16][768]
    float* bqk    = (float*)(ws + 154558464);                         // [1536]
    float* qfs    = (float*)(ws + 154564608);                         // [96][4096]
    float* parts1 = (float*)(ws + 156137472);                         // [96][8][72]
    float* parts2 = (float*)(ws + 156358656);                         // [96][8][72]

    prep_all<<<26318, 256, 0, stream>>>(hs, Wq, Wk, Wt, Wqa, bq, bk,
                                        hs_bf, Wqk_bf, Wt_bf, Wqa_bf, bqk);

    // q|k projection: M=32768, N=1536, K=768 -> split q_c / k_c
    gemm8<<<(M_TOT / 256) * 6, 512, 0, stream>>>(
        hs_bf, Wqk_bf, bqk, q_c, k_c, 6);

    qfs_kernel<<<M_TOT / 64, 256, 0, stream>>>(q_c, Wqa_bf, bqa, mask, qfs);
    pool1_kernel<<<NB * NH * 8, 256, 0, stream>>>(qfs, q_c, parts1);
    pool2_kernel<<<NB * NH * 8, 256, 0, stream>>>(parts1, k_c, mask, parts2);
    gatedw_kernel<<<NB * 96, 256, 0, stream>>>(parts2, Wt_bf, W8);

    // out = q @ (Wt*pk_b)^T + bt + q : M=32768, N=768 (256x128, 3-buf), K=768
    gemm3<<<(M_TOT / 256) * 6, 512, 0, stream>>>(
        q_c, W8, bt, out, q_c);
}